// Round 12
// baseline (363.084 us; speedup 1.0000x reference)
//
#include <hip/hip_runtime.h>

#define SPB 5
#define TPB 256
// x: padded plane stride 50 (49->50, 8B-aligned patch bases), sample stride 49*50
#define XPL 50
#define XSS 2450
// h1 overlay: padded plane stride 26, strides d:26 l:130 o:650 s:1300
#define H1PL 26
#define H1L  130
#define H1O  650
#define H1S  1300

__global__ __launch_bounds__(TPB, 2)
void conv4d_fused(const float* __restrict__ x,
                  const float* __restrict__ w1, const float* __restrict__ b1,
                  const float* __restrict__ w2, const float* __restrict__ b2,
                  float* __restrict__ out, int B)
{
    // ONLY x (and its h1 overlay) lives in LDS: 5*2450*4 = 49 KB -> 3 blocks/CU.
    // Weights/biases are read straight from global (L1/K$-resident, 3.3 KB
    // total): their reads ride the near-idle VMEM pipe instead of adding
    // ~4.7k cycles/block (25%) to the saturated LDS pipe.
    __shared__ __align__(8) float s_x[SPB * XSS];

    const int t  = threadIdx.x;
    const int s0 = blockIdx.x * SPB;
    const int ns = min(SPB, B - s0);

    // ---- stage x with plane padding 49->50 (pads never read).
    //      Incremental (plane, col) walk: 256 = 5*49 + 11 -> pl += 5, c += 11
    //      per step with one wrap check (replaces per-element magic-division).
    {
        const float* xp = x + (size_t)s0 * 2401;
        const int n = ns * 2401;
        int pl = t / 49;
        int c  = t - pl * 49;
        for (int i = t; i < n; i += TPB) {
            s_x[pl * XPL + c] = xp[i];
            pl += 5; c += 11;
            if (c >= 49) { c -= 49; pl += 1; }
        }
    }
    __syncthreads();

    // ---- phase 1: task = (s, o, l, d) -> full 5x5 plane in regs.
    //      250/256 threads, 4 waves (proven structure). Patch reads are
    //      ds_read_b64 (24 pairs + 1) from LDS; weights from global.
    float acc[5][5];
    int h1b = 0;
    const bool act1 = t < ns * 50;
    if (act1) {
        int s = t / 50;
        int r = t % 50;
        int o = r / 25; r %= 25;
        int l = r / 5, d = r % 5;
        h1b = s * H1S + o * H1O + l * H1L + d * H1PL;

        const float bias = b1[o];
        #pragma unroll
        for (int h = 0; h < 5; ++h)
            #pragma unroll
            for (int w = 0; w < 5; ++w) acc[h][w] = bias;

        const float* xs = s_x + s * XSS;
        const float* wo = w1 + o * 81;          // global, L1/K$-hot
        #pragma unroll
        for (int kl = 0; kl < 3; ++kl)
        #pragma unroll
        for (int kd = 0; kd < 3; ++kd) {
            float p[49];
            const float* xp = xs + ((l + kl) * 7 + (d + kd)) * XPL; // even idx
            const float2* q = (const float2*)xp;
            #pragma unroll
            for (int i = 0; i < 24; ++i) {
                const float2 f = q[i];
                p[2 * i] = f.x; p[2 * i + 1] = f.y;
            }
            p[48] = xp[48];
            const float* wp = wo + kl * 27 + kd * 9;
            #pragma unroll
            for (int kh = 0; kh < 3; ++kh)
            #pragma unroll
            for (int kw = 0; kw < 3; ++kw) {
                const float wv = wp[kh * 3 + kw];
                #pragma unroll
                for (int h = 0; h < 5; ++h)
                #pragma unroll
                for (int w = 0; w < 5; ++w)
                    acc[h][w] += p[(h + kh) * 7 + (w + kw)] * wv;
            }
        }
    }
    __syncthreads();   // all phase-1 reads of s_x complete -> region dead

    // ---- write h1 (ReLU) into overlay as float2 (base even)
    if (act1) {
        float* hp = s_x + h1b;
        #pragma unroll
        for (int i = 0; i < 12; ++i) {
            float2 f;
            f.x = fmaxf(acc[(2 * i) / 5][(2 * i) % 5], 0.0f);
            f.y = fmaxf(acc[(2 * i + 1) / 5][(2 * i + 1) % 5], 0.0f);
            ((float2*)hp)[i] = f;
        }
        hp[24] = fmaxf(acc[4][4], 0.0f);
    }
    __syncthreads();

    // ---- phase 2: task = (s, o2, l, d) -> full 3x3 plane in regs.
    //      180/256 threads. h1 plane reads are 12 x b64 + 1; weights global.
    if (t < ns * 36) {
        int s = t / 36;
        int r = t % 36;
        int o2 = r / 9; r %= 9;
        int l = r / 3, d = r % 3;

        float a2[3][3];
        const float bias = b2[o2];
        #pragma unroll
        for (int h = 0; h < 3; ++h)
            #pragma unroll
            for (int w = 0; w < 3; ++w) a2[h][w] = bias;

        #pragma unroll
        for (int c = 0; c < 2; ++c) {
            const float* hs = s_x + s * H1S + c * H1O;
            const float* wb = w2 + o2 * 162 + c * 81;   // global, L1/K$-hot
            #pragma unroll
            for (int kl = 0; kl < 3; ++kl)
            #pragma unroll
            for (int kd = 0; kd < 3; ++kd) {
                float p[25];
                const float* pp = hs + (l + kl) * H1L + (d + kd) * H1PL; // even
                const float2* q = (const float2*)pp;
                #pragma unroll
                for (int i = 0; i < 12; ++i) {
                    const float2 f = q[i];
                    p[2 * i] = f.x; p[2 * i + 1] = f.y;
                }
                p[24] = pp[24];
                const float* wp = wb + kl * 27 + kd * 9;
                #pragma unroll
                for (int kh = 0; kh < 3; ++kh)
                #pragma unroll
                for (int kw = 0; kw < 3; ++kw) {
                    const float wv = wp[kh * 3 + kw];
                    #pragma unroll
                    for (int h = 0; h < 3; ++h)
                    #pragma unroll
                    for (int w = 0; w < 3; ++w)
                        a2[h][w] += p[(h + kh) * 5 + (w + kw)] * wv;
                }
            }
        }
        float* op = out + (size_t)(s0 + s) * 324 + o2 * 81 + l * 27 + d * 9;
        #pragma unroll
        for (int h = 0; h < 3; ++h)
        #pragma unroll
        for (int w = 0; w < 3; ++w)
            op[h * 3 + w] = fmaxf(a2[h][w], 0.0f);
    }
}

extern "C" void kernel_launch(void* const* d_in, const int* in_sizes, int n_in,
                              void* d_out, int out_size, void* d_ws, size_t ws_size,
                              hipStream_t stream)
{
    const float* x  = (const float*)d_in[0];
    const float* w1 = (const float*)d_in[1];
    const float* b1 = (const float*)d_in[2];
    const float* w2 = (const float*)d_in[3];
    const float* b2 = (const float*)d_in[4];
    float* out = (float*)d_out;

    const int B = in_sizes[0] / 2401;          // 16384
    const int grid = (B + SPB - 1) / SPB;      // 3277 blocks
    conv4d_fused<<<grid, TPB, 0, stream>>>(x, w1, b1, w2, b2, out, B);
}